// Round 1
// baseline (148.724 us; speedup 1.0000x reference)
//
#include <hip/hip_runtime.h>
#include <math.h>

// Problem constants (from reference): B,H,K,L,V = 4096,1024,10,64,80
constexpr int Bn = 4096;
constexpr int Hn = 1024;
constexpr int Kn = 10;
constexpr int Ln = 64;
constexpr int Vn = 80;
constexpr int NJ = 3 * Kn;   // 30
constexpr int R  = 4;        // batch rows per block (phi kernel)
constexpr int NT = 256;
constexpr int RW = 2;        // batch rows per block (einsum kernel)

// ---------------------------------------------------------------------------
// Kernel 1 (producer): phi[b][l] = sum_k alpha*exp(-beta*(kappa-l)^2)
// Streams x (16.8 MB), W stays L2-resident. Writes phi [B,64] = 1 MB to ws.
// ---------------------------------------------------------------------------
__global__ __launch_bounds__(NT) void phi_kernel(
    const float* __restrict__ x,      // [B,H]
    const float* __restrict__ W,      // [H,3K]
    const float* __restrict__ bias,   // [3K]
    float* __restrict__ phi)          // [B,L] (workspace)
{
    __shared__ float xs[R * Hn];      // 16 KB
    __shared__ float part[R * 256];   // 4 KB
    __shared__ float abk[R * NJ];     // 480 B

    const int t    = threadIdx.x;
    const int row0 = blockIdx.x * R;

    // ---- Stage x rows into LDS (coalesced float4) ----
    const float4* x4  = (const float4*)x;
    float4*       xs4 = (float4*)xs;
#pragma unroll
    for (int r = 0; r < R; ++r)
        xs4[r * (Hn / 4) + t] = x4[(size_t)(row0 + r) * (Hn / 4) + t];
    __syncthreads();

    // ---- GEMM partials: out[r][j] = sum_h x[r][h] * W[h][j] ----
    const int j = t & 31;
    const int g = t >> 5;
    float acc0 = 0.f, acc1 = 0.f, acc2 = 0.f, acc3 = 0.f;
    if (j < NJ) {
        const float* Wp = W + j;
        const int h0 = g * 128;
#pragma unroll 4
        for (int ii = 0; ii < 128; ii += 4) {
            const int h  = h0 + ii;
            const int h4 = h >> 2;
            float4 xa = xs4[0 * (Hn / 4) + h4];   // LDS broadcast across j-lanes
            float4 xb = xs4[1 * (Hn / 4) + h4];
            float4 xc = xs4[2 * (Hn / 4) + h4];
            float4 xd = xs4[3 * (Hn / 4) + h4];
            float w0 = Wp[(h + 0) * NJ];
            float w1 = Wp[(h + 1) * NJ];
            float w2 = Wp[(h + 2) * NJ];
            float w3 = Wp[(h + 3) * NJ];
            acc0 += w0 * xa.x + w1 * xa.y + w2 * xa.z + w3 * xa.w;
            acc1 += w0 * xb.x + w1 * xb.y + w2 * xb.z + w3 * xb.w;
            acc2 += w0 * xc.x + w1 * xc.y + w2 * xc.z + w3 * xc.w;
            acc3 += w0 * xd.x + w1 * xd.y + w2 * xd.z + w3 * xd.w;
        }
    }
    part[0 * 256 + g * 32 + j] = acc0;
    part[1 * 256 + g * 32 + j] = acc1;
    part[2 * 256 + g * 32 + j] = acc2;
    part[3 * 256 + g * 32 + j] = acc3;
    __syncthreads();

    // ---- Reduce partials, add bias, exp ----
    if (t < R * NJ) {  // 120 threads
        const int r = t / NJ, jj = t % NJ;
        float s = bias[jj];
#pragma unroll
        for (int gg = 0; gg < 8; ++gg) s += part[r * 256 + gg * 32 + jj];
        abk[r * NJ + jj] = __expf(s);
    }
    __syncthreads();

    // ---- phi[r][l], written straight to global (coalesced: t -> consecutive) ----
    {
        const int r = t >> 6, l = t & 63;
        const float lf = (float)l;
        const float* ab = abk + r * NJ;
        float ph = 0.f;
#pragma unroll
        for (int k = 0; k < Kn; ++k) {
            float a  = ab[k];
            float bt = ab[Kn + k];
            float kp = ab[2 * Kn + k];
            float d  = kp - lf;
            ph += a * __expf(-bt * d * d);
        }
        phi[(size_t)(row0 + r) * Ln + l] = ph;
    }
}

// ---------------------------------------------------------------------------
// Kernel 2 (consumer): out[b][v] = sum_l phi[b][l] * chars[b][l][v]
// Pure streaming kernel. RW=2 rows/block -> 2048 blocks, 8 blocks/CU,
// 32 waves/CU resident: maximal outstanding-load depth for the chars stream.
// ---------------------------------------------------------------------------
__global__ __launch_bounds__(NT) void einsum_kernel(
    const float* __restrict__ phi,    // [B,L]
    const float* __restrict__ chars,  // [B,L,V]
    float* __restrict__ out)          // [B,V]
{
    __shared__ float  phi_s[RW * Ln];         // 512 B
    __shared__ float4 cpart[RW * 12 * 20];    // 7.68 KB

    const int t    = threadIdx.x;
    const int row0 = blockIdx.x * RW;

    if (t < RW * Ln)  // 128 contiguous floats
        phi_s[t] = phi[(size_t)row0 * Ln + t];
    __syncthreads();

    const float4* c4 = (const float4*)chars;  // row stride = 64*80/4 = 1280
    if (t < 240) {
        const int v4 = t % 20;   // float4 column
        const int g  = t / 20;   // 12 l-groups
        float4 s0 = make_float4(0.f, 0.f, 0.f, 0.f);
        float4 s1 = s0;
        for (int l = g; l < Ln; l += 12) {
            const int off = l * 20 + v4;
            float4 cA = c4[(size_t)(row0 + 0) * 1280 + off];
            float4 cB = c4[(size_t)(row0 + 1) * 1280 + off];
            float p0 = phi_s[l];
            float p1 = phi_s[Ln + l];
            s0.x += p0 * cA.x; s0.y += p0 * cA.y; s0.z += p0 * cA.z; s0.w += p0 * cA.w;
            s1.x += p1 * cB.x; s1.y += p1 * cB.y; s1.z += p1 * cB.z; s1.w += p1 * cB.w;
        }
        cpart[(0 * 12 + g) * 20 + v4] = s0;
        cpart[(1 * 12 + g) * 20 + v4] = s1;
    }
    __syncthreads();

    if (t < RW * 20) {  // 40 threads finalize
        const int r  = t / 20;
        const int vv = t % 20;
        float4 s = make_float4(0.f, 0.f, 0.f, 0.f);
#pragma unroll
        for (int gg = 0; gg < 12; ++gg) {
            float4 p = cpart[(r * 12 + gg) * 20 + vv];
            s.x += p.x; s.y += p.y; s.z += p.z; s.w += p.w;
        }
        ((float4*)out)[(size_t)(row0 + r) * 20 + vv] = s;
    }
}

// ---------------------------------------------------------------------------
// Fused fallback (previous best kernel) — used only if ws too small.
// ---------------------------------------------------------------------------
__global__ __launch_bounds__(NT) void window_kernel(
    const float* __restrict__ x,
    const float* __restrict__ chars,
    const float* __restrict__ W,
    const float* __restrict__ bias,
    float* __restrict__ out)
{
    __shared__ float  xs[R * Hn];
    __shared__ float  part[R * 256];
    __shared__ float  abk[R * NJ];
    __shared__ float  phi_s[R * Ln];
    __shared__ float4 cpart[R * 12 * 20];

    const int t    = threadIdx.x;
    const int row0 = blockIdx.x * R;

    const float4* x4  = (const float4*)x;
    float4*       xs4 = (float4*)xs;
#pragma unroll
    for (int r = 0; r < R; ++r)
        xs4[r * (Hn / 4) + t] = x4[(size_t)(row0 + r) * (Hn / 4) + t];
    __syncthreads();

    const int j = t & 31;
    const int g = t >> 5;
    float acc0 = 0.f, acc1 = 0.f, acc2 = 0.f, acc3 = 0.f;
    if (j < NJ) {
        const float* Wp = W + j;
        const int h0 = g * 128;
#pragma unroll 4
        for (int ii = 0; ii < 128; ii += 4) {
            const int h  = h0 + ii;
            const int h4 = h >> 2;
            float4 xa = xs4[0 * (Hn / 4) + h4];
            float4 xb = xs4[1 * (Hn / 4) + h4];
            float4 xc = xs4[2 * (Hn / 4) + h4];
            float4 xd = xs4[3 * (Hn / 4) + h4];
            float w0 = Wp[(h + 0) * NJ];
            float w1 = Wp[(h + 1) * NJ];
            float w2 = Wp[(h + 2) * NJ];
            float w3 = Wp[(h + 3) * NJ];
            acc0 += w0 * xa.x + w1 * xa.y + w2 * xa.z + w3 * xa.w;
            acc1 += w0 * xb.x + w1 * xb.y + w2 * xb.z + w3 * xb.w;
            acc2 += w0 * xc.x + w1 * xc.y + w2 * xc.z + w3 * xc.w;
            acc3 += w0 * xd.x + w1 * xd.y + w2 * xd.z + w3 * xd.w;
        }
    }
    part[0 * 256 + g * 32 + j] = acc0;
    part[1 * 256 + g * 32 + j] = acc1;
    part[2 * 256 + g * 32 + j] = acc2;
    part[3 * 256 + g * 32 + j] = acc3;
    __syncthreads();

    if (t < R * NJ) {
        const int r = t / NJ, jj = t % NJ;
        float s = bias[jj];
#pragma unroll
        for (int gg = 0; gg < 8; ++gg) s += part[r * 256 + gg * 32 + jj];
        abk[r * NJ + jj] = __expf(s);
    }
    __syncthreads();

    {
        const int r = t >> 6, l = t & 63;
        const float lf = (float)l;
        const float* ab = abk + r * NJ;
        float ph = 0.f;
#pragma unroll
        for (int k = 0; k < Kn; ++k) {
            float a  = ab[k];
            float bt = ab[Kn + k];
            float kp = ab[2 * Kn + k];
            float d  = kp - lf;
            ph += a * __expf(-bt * d * d);
        }
        phi_s[r * Ln + l] = ph;
    }
    __syncthreads();

    const float4* c4 = (const float4*)chars;
    if (t < 240) {
        const int v4  = t % 20;
        const int g12 = t / 20;
        float4 s0 = make_float4(0.f, 0.f, 0.f, 0.f);
        float4 s1 = s0, s2 = s0, s3 = s0;
        for (int l = g12; l < Ln; l += 12) {
            const int off = l * 20 + v4;
            float4 cA = c4[(size_t)(row0 + 0) * 1280 + off];
            float4 cB = c4[(size_t)(row0 + 1) * 1280 + off];
            float4 cC = c4[(size_t)(row0 + 2) * 1280 + off];
            float4 cD = c4[(size_t)(row0 + 3) * 1280 + off];
            float p0 = phi_s[0 * Ln + l];
            float p1 = phi_s[1 * Ln + l];
            float p2 = phi_s[2 * Ln + l];
            float p3 = phi_s[3 * Ln + l];
            s0.x += p0 * cA.x; s0.y += p0 * cA.y; s0.z += p0 * cA.z; s0.w += p0 * cA.w;
            s1.x += p1 * cB.x; s1.y += p1 * cB.y; s1.z += p1 * cB.z; s1.w += p1 * cB.w;
            s2.x += p2 * cC.x; s2.y += p2 * cC.y; s2.z += p2 * cC.z; s2.w += p2 * cC.w;
            s3.x += p3 * cD.x; s3.y += p3 * cD.y; s3.z += p3 * cD.z; s3.w += p3 * cD.w;
        }
        cpart[(0 * 12 + g12) * 20 + v4] = s0;
        cpart[(1 * 12 + g12) * 20 + v4] = s1;
        cpart[(2 * 12 + g12) * 20 + v4] = s2;
        cpart[(3 * 12 + g12) * 20 + v4] = s3;
    }
    __syncthreads();

    if (t < 80) {
        const int r  = t / 20;
        const int vv = t % 20;
        float4 s = make_float4(0.f, 0.f, 0.f, 0.f);
#pragma unroll
        for (int gg = 0; gg < 12; ++gg) {
            float4 p = cpart[(r * 12 + gg) * 20 + vv];
            s.x += p.x; s.y += p.y; s.z += p.z; s.w += p.w;
        }
        ((float4*)out)[(size_t)(row0 + r) * 20 + vv] = s;
    }
}

extern "C" void kernel_launch(void* const* d_in, const int* in_sizes, int n_in,
                              void* d_out, int out_size, void* d_ws, size_t ws_size,
                              hipStream_t stream) {
    const float* x     = (const float*)d_in[0];
    const float* chars = (const float*)d_in[1];
    const float* W     = (const float*)d_in[2];
    const float* bias  = (const float*)d_in[3];
    float* out = (float*)d_out;

    const size_t phi_bytes = (size_t)Bn * Ln * sizeof(float);  // 1 MB
    if (d_ws != nullptr && ws_size >= phi_bytes) {
        float* phi = (float*)d_ws;
        phi_kernel<<<Bn / R, NT, 0, stream>>>(x, W, bias, phi);
        einsum_kernel<<<Bn / RW, NT, 0, stream>>>(phi, chars, out);
    } else {
        window_kernel<<<Bn / R, NT, 0, stream>>>(x, chars, W, bias, out);
    }
}

// Round 2
// 148.454 us; speedup vs baseline: 1.0018x; 1.0018x over previous
//
#include <hip/hip_runtime.h>
#include <math.h>
#include <stdint.h>

// Problem constants: B,H,K,L,V = 4096,1024,10,64,80
constexpr int Bn = 4096;
constexpr int Hn = 1024;
constexpr int Kn = 10;
constexpr int Ln = 64;
constexpr int Vn = 80;
constexpr int NJ = 3 * Kn;   // 30
constexpr int R  = 2;        // batch rows per block
constexpr int NT = 256;

// async global->LDS, 16B per lane, wave-uniform LDS base
typedef const __attribute__((address_space(1))) uint32_t glb_u32;
typedef __attribute__((address_space(3))) uint32_t lds_u32;
__device__ __forceinline__ void gload_lds16(const void* g, void* l) {
    __builtin_amdgcn_global_load_lds((glb_u32*)g, (lds_u32*)l, 16, 0, 0);
}

// LDS budget: 40960 (cs) + 8192 (xs, reused as cpart) + 2048 (red) + 240 + 512
//           = 51952 B  -> 3 blocks/CU (160 KB LDS), 12 waves/CU.
__global__ __launch_bounds__(NT) void window_fused(
    const float* __restrict__ x,      // [B,H]
    const float* __restrict__ chars,  // [B,L,V]
    const float* __restrict__ W,      // [H,3K]
    const float* __restrict__ bias,   // [3K]
    float* __restrict__ out)          // [B,V]
{
    __shared__ float4 cs4[R * Ln * Vn / 4];  // 40960 B, linear copy of block's chars
    __shared__ float4 xs4[R * Hn / 4];       // 8192 B x stage; reused as cpart in einsum
    __shared__ float  red[R * 256];          // GEMM partials
    __shared__ float  abk[R * NJ];           // exp(x@W+b)
    __shared__ float  phi_s[R * Ln];

    const int t    = threadIdx.x;
    const int lane = t & 63;
    const int w    = t >> 6;                 // wave id 0..3
    const int row0 = blockIdx.x * R;

    // ---- Phase 0a: x -> LDS first (its vmcnt wait must NOT drain chars queue),
    //      bias preloaded for the same reason.
    const float4* xg4 = (const float4*)(x + (size_t)row0 * Hn);  // 8 KB contiguous
    float4 xa = xg4[t];
    float4 xb = xg4[NT + t];
    float bias_v = 0.f;
    if (t < R * NJ) bias_v = bias[t % NJ];
    xs4[t]      = xa;   // compiler inserts vmcnt wait for xa/xb here (chars not yet issued)
    xs4[NT + t] = xb;

    // ---- Phase 0b: fire-and-forget chars -> LDS. Block panel is 40960 B
    //      CONTIGUOUS in global (2 adjacent batch rows). 40 chunks of 1 KB,
    //      10 per wave; LDS dest is wave-uniform base + lane*16 (linear copy).
    const char* cg = (const char*)(chars + (size_t)row0 * Ln * Vn);
    char*       cl = (char*)cs4;
#pragma unroll
    for (int i = 0; i < 10; ++i) {
        const int off = (w * 10 + i) * 1024;
        gload_lds16(cg + off + lane * 16, cl + off);
    }

    // x visible to all waves; chars still in flight (lgkm-only barrier, NOT __syncthreads)
    asm volatile("s_waitcnt lgkmcnt(0)" ::: "memory");
    __builtin_amdgcn_s_barrier();
    __builtin_amdgcn_sched_barrier(0);

    // ---- Phase 1: GEMM partials out[r][j] = sum_h x[r][h]*W[h][j] ----
    const int j = t & 31;
    const int g = t >> 5;
    float acc0 = 0.f, acc1 = 0.f;
    if (j < NJ) {
        const float* Wp = W + j;
        const int h0 = g * 128;
#pragma unroll 4
        for (int ii = 0; ii < 128; ii += 4) {
            const int h  = h0 + ii;
            const int h4 = h >> 2;
            float4 va = xs4[h4];             // LDS broadcast across j-lanes
            float4 vb = xs4[(Hn / 4) + h4];
            float w0 = Wp[(h + 0) * NJ];
            float w1 = Wp[(h + 1) * NJ];
            float w2 = Wp[(h + 2) * NJ];
            float w3 = Wp[(h + 3) * NJ];
            acc0 += w0 * va.x + w1 * va.y + w2 * va.z + w3 * va.w;
            acc1 += w0 * vb.x + w1 * vb.y + w2 * vb.z + w3 * vb.w;
        }
    }
    red[0 * 256 + g * 32 + j] = acc0;
    red[1 * 256 + g * 32 + j] = acc1;
    asm volatile("s_waitcnt lgkmcnt(0)" ::: "memory");
    __builtin_amdgcn_s_barrier();
    __builtin_amdgcn_sched_barrier(0);

    // ---- Phase 2: reduce + bias + exp ----
    if (t < R * NJ) {  // 60 threads
        const int r = t / NJ, jj = t % NJ;
        float s = bias_v;
#pragma unroll
        for (int gg = 0; gg < 8; ++gg) s += red[r * 256 + gg * 32 + jj];
        abk[r * NJ + jj] = __expf(s);
    }
    asm volatile("s_waitcnt lgkmcnt(0)" ::: "memory");
    __builtin_amdgcn_s_barrier();
    __builtin_amdgcn_sched_barrier(0);

    // ---- Phase 3: phi[r][l] = sum_k alpha*exp(-beta*(kappa-l)^2) ----
    if (t < R * Ln) {  // 128 threads
        const int r = t >> 6, l = t & 63;
        const float lf = (float)l;
        const float* ab = abk + r * NJ;
        float ph = 0.f;
#pragma unroll
        for (int k = 0; k < Kn; ++k) {
            float a  = ab[k];
            float bt = ab[Kn + k];
            float kp = ab[2 * Kn + k];
            float d  = kp - lf;
            ph += a * __expf(-bt * d * d);
        }
        phi_s[r * Ln + l] = ph;
    }

    // Full drain: chars guaranteed in LDS + phi_s visible.
    __syncthreads();

    // ---- Phase 4: window[r][v] = sum_l phi[r][l]*chars[r][l][v], all from LDS ----
    float4* cpart = (float4*)xs4;  // xs dead; reuse 7680 of its 8192 B
    if (t < 240) {
        const int v4  = t % 20;   // float4 column
        const int g12 = t / 20;   // 12 l-groups
        float4 s0 = make_float4(0.f, 0.f, 0.f, 0.f);
        float4 s1 = s0;
        for (int l = g12; l < Ln; l += 12) {
            // lane->index map is contiguous: conflict-free ds_read_b128
            float4 cA = cs4[l * 20 + v4];
            float4 cB = cs4[1280 + l * 20 + v4];
            float p0 = phi_s[l];
            float p1 = phi_s[Ln + l];
            s0.x += p0 * cA.x; s0.y += p0 * cA.y; s0.z += p0 * cA.z; s0.w += p0 * cA.w;
            s1.x += p1 * cB.x; s1.y += p1 * cB.y; s1.z += p1 * cB.z; s1.w += p1 * cB.w;
        }
        cpart[(0 * 12 + g12) * 20 + v4] = s0;
        cpart[(1 * 12 + g12) * 20 + v4] = s1;
    }
    __syncthreads();

    if (t < R * 20) {  // 40 threads finalize
        const int r  = t / 20;
        const int vv = t % 20;
        float4 s = make_float4(0.f, 0.f, 0.f, 0.f);
#pragma unroll
        for (int gg = 0; gg < 12; ++gg) {
            float4 p = cpart[(r * 12 + gg) * 20 + vv];
            s.x += p.x; s.y += p.y; s.z += p.z; s.w += p.w;
        }
        ((float4*)out)[(size_t)(row0 + r) * 20 + vv] = s;
    }
}

extern "C" void kernel_launch(void* const* d_in, const int* in_sizes, int n_in,
                              void* d_out, int out_size, void* d_ws, size_t ws_size,
                              hipStream_t stream) {
    const float* x     = (const float*)d_in[0];
    const float* chars = (const float*)d_in[1];
    const float* W     = (const float*)d_in[2];
    const float* bias  = (const float*)d_in[3];
    float* out = (float*)d_out;

    window_fused<<<Bn / R, NT, 0, stream>>>(x, chars, W, bias, out);
}